// Round 2
// baseline (126.469 us; speedup 1.0000x reference)
//
#include <hip/hip_runtime.h>
#include <stdint.h>

typedef __bf16 bf16;
typedef bf16 bf16x8 __attribute__((ext_vector_type(8)));
typedef float floatx4 __attribute__((ext_vector_type(4)));

#define INV_T 2.0f                        // 1 / TEMPERATURE
#define EXP2_SCALE 2.8853900817779268f    // INV_T * log2(e)

// ---------------------------------------------------------------------------
// Kernel 1: L2-normalize each row of proj_1 / proj_2 (fp32), write bf16 reps.
// One wave per row of 128 floats; 2 elements/lane.
// ---------------------------------------------------------------------------
__global__ __launch_bounds__(256) void nrm_kernel(const float* __restrict__ p1,
                                                  const float* __restrict__ p2,
                                                  unsigned* __restrict__ reps) {
    int gt   = blockIdx.x * 256 + threadIdx.x;
    int row  = gt >> 6;
    int lane = gt & 63;
    const float* srcRow = (row < 4096) ? (p1 + (size_t)row * 128)
                                       : (p2 + (size_t)(row - 4096) * 128);
    float2 v = ((const float2*)srcRow)[lane];
    float ss = v.x * v.x + v.y * v.y;
#pragma unroll
    for (int s = 1; s < 64; s <<= 1) ss += __shfl_xor(ss, s, 64);
    float inv = 1.0f / fmaxf(sqrtf(ss), 1e-12f);
    union { bf16 h[2]; unsigned u; } pk;
    pk.h[0] = (bf16)(v.x * inv);
    pk.h[1] = (bf16)(v.y * inv);
    reps[(size_t)row * 64 + lane] = pk.u;   // row-major [8192][128] bf16
}

// ---------------------------------------------------------------------------
// Kernel 2: rowsum partials + positive-pair dot. NO LDS, NO barriers.
// A-frags and B-frags are both 16B-contiguous slices of reps rows -> direct
// coalesced global loads (B tile reused across 64 blocks via L1/L2).
// Grid: (8 col-groups of 1024, 64 row-tiles of 128). Block = 256 = 4 waves.
// Wave w covers rows wRow..+63, cols wCol..+63 of its 128x128 tile.
// Output: rowsum16[(cg*2 + colHalf)*8192 + row] — each slot written once.
// ---------------------------------------------------------------------------
__global__ __launch_bounds__(256, 2) void sim_kernel(const bf16* __restrict__ reps,
                                                     float* __restrict__ rowsum16,
                                                     float* __restrict__ pos) {
    const int cg   = blockIdx.x;   // 0..7
    const int bi   = blockIdx.y;   // 0..63
    const int tid  = threadIdx.x;
    const int w    = tid >> 6;     // wave 0..3
    const int lane = tid & 63;
    const int quad = lane >> 4;
    const int lcol = lane & 15;

    const int rowTileBase = bi * 128;
    const int wRow = (w >> 1) * 64;
    const int wCol = (w & 1) * 64;

    // preload A fragments straight from global (constant across all B tiles)
    // lane holds A[m = lcol][k = quad*8 + j], j=0..7 -> 16B of row (base+m)
    bf16x8 aF[4][4];
#pragma unroll
    for (int mi = 0; mi < 4; mi++)
#pragma unroll
        for (int ks = 0; ks < 4; ks++) {
            int r = rowTileBase + wRow + mi * 16 + lcol;
            int k = ks * 32 + quad * 8;
            aF[mi][ks] = *(const bf16x8*)(reps + (size_t)r * 128 + k);
        }

    float rs[16];   // per-lane rowsum partials, index = mi*4 + reg
#pragma unroll
    for (int i = 0; i < 16; i++) rs[i] = 0.0f;

    for (int cj = 0; cj < 8; cj++) {
        const int colTileBase = cg * 1024 + cj * 128;

        floatx4 acc[4][4];
        const floatx4 zf = {0.0f, 0.0f, 0.0f, 0.0f};
#pragma unroll
        for (int mi = 0; mi < 4; mi++)
#pragma unroll
            for (int ni = 0; ni < 4; ni++) acc[mi][ni] = zf;

#pragma unroll
        for (int ni = 0; ni < 4; ni++) {
            const int c = colTileBase + wCol + ni * 16 + lcol;
            const bf16* bRow = reps + (size_t)c * 128;
            bf16x8 bF[4];
#pragma unroll
            for (int ks = 0; ks < 4; ks++)
                bF[ks] = *(const bf16x8*)(bRow + ks * 32 + quad * 8);
#pragma unroll
            for (int ks = 0; ks < 4; ks++)
#pragma unroll
                for (int mi = 0; mi < 4; mi++)
                    acc[mi][ni] = __builtin_amdgcn_mfma_f32_16x16x32_bf16(
                        aF[mi][ks], bF[ks], acc[mi][ni], 0, 0, 0);
        }

        // fused epilogue: exp2(scale*s) + rowsum partials
        const int rowB = rowTileBase + wRow;
        const int colB = colTileBase + wCol;
        const bool diagT = (colTileBase == rowTileBase);
        const bool partT = (colTileBase == ((rowTileBase + 4096) & 8191));
        if (diagT | partT) {
#pragma unroll
            for (int mi = 0; mi < 4; mi++)
#pragma unroll
                for (int ni = 0; ni < 4; ni++)
#pragma unroll
                    for (int r = 0; r < 4; r++) {
                        int grow = rowB + mi * 16 + quad * 4 + r;
                        int gcol = colB + ni * 16 + lcol;
                        float s = acc[mi][ni][r];
                        if (partT && gcol == ((grow + 4096) & 8191)) pos[grow] = s;
                        float e = __builtin_amdgcn_exp2f(s * EXP2_SCALE);
                        if (diagT && grow == gcol) e = 0.0f;   // mask j == i
                        rs[mi * 4 + r] += e;
                    }
        } else {
#pragma unroll
            for (int mi = 0; mi < 4; mi++)
#pragma unroll
                for (int ni = 0; ni < 4; ni++)
#pragma unroll
                    for (int r = 0; r < 4; r++)
                        rs[mi * 4 + r] += __builtin_amdgcn_exp2f(acc[mi][ni][r] * EXP2_SCALE);
        }
    }

    // sum over cols handled by this wave: reduce across lcol (lane bits 0-3)
#pragma unroll
    for (int s = 1; s < 16; s <<= 1)
#pragma unroll
        for (int k = 0; k < 16; k++) rs[k] += __shfl_xor(rs[k], s, 64);

    if (lcol == 0) {
        float* dst = rowsum16 + (size_t)(cg * 2 + (w & 1)) * 8192;
#pragma unroll
        for (int k = 0; k < 16; k++) {
            int grow = rowTileBase + wRow + (k >> 2) * 16 + quad * 4 + (k & 3);
            dst[grow] = rs[k];   // unique slot, written exactly once
        }
    }
}

// ---------------------------------------------------------------------------
// Kernel 3: loss = (1/8192) * sum_i [ log(sum_p rowsum16[p][i]) - 2*pos_i ]
// Single block -> direct write to out, no memset/atomics needed.
// ---------------------------------------------------------------------------
__global__ __launch_bounds__(1024) void fin_kernel(const float* __restrict__ rowsum16,
                                                   const float* __restrict__ pos,
                                                   float* __restrict__ out) {
    float v = 0.0f;
#pragma unroll
    for (int rr = 0; rr < 8; rr++) {
        int r = rr * 1024 + threadIdx.x;
        float d = 0.0f;
#pragma unroll
        for (int p = 0; p < 16; p++) d += rowsum16[p * 8192 + r];
        v += logf(d) - pos[r] * INV_T;
    }
#pragma unroll
    for (int s = 1; s < 64; s <<= 1) v += __shfl_xor(v, s, 64);
    __shared__ float red[16];
    if ((threadIdx.x & 63) == 0) red[threadIdx.x >> 6] = v;
    __syncthreads();
    if (threadIdx.x == 0) {
        float t = 0.0f;
#pragma unroll
        for (int i = 0; i < 16; i++) t += red[i];
        *out = t * (1.0f / 8192.0f);
    }
}

extern "C" void kernel_launch(void* const* d_in, const int* in_sizes, int n_in,
                              void* d_out, int out_size, void* d_ws, size_t ws_size,
                              hipStream_t stream) {
    const float* p1 = (const float*)d_in[0];
    const float* p2 = (const float*)d_in[1];
    float* out = (float*)d_out;

    char* ws       = (char*)d_ws;
    bf16* reps     = (bf16*)ws;                          // 2 MB
    float* rowsum16 = (float*)(ws + (2u << 20));         // 16*8192*4 = 512 KB
    float* pos      = (float*)(ws + (2u << 20) + (512u << 10)); // 32 KB

    nrm_kernel<<<2048, 256, 0, stream>>>(p1, p2, (unsigned*)reps);
    sim_kernel<<<dim3(8, 64), 256, 0, stream>>>(reps, rowsum16, pos);
    fin_kernel<<<1, 1024, 0, stream>>>(rowsum16, pos, out);
}